// Round 4
// baseline (353.716 us; speedup 1.0000x reference)
//
#include <hip/hip_runtime.h>

#define N_NODES  50000
#define N_EDGES  800000
#define N_GRAPHS 512
#define HID      64
#define NCLS     5
#define SCAN_B   ((N_NODES + 255) / 256)   // 196

typedef __attribute__((ext_vector_type(8))) short bf16x8;
typedef __attribute__((ext_vector_type(4))) float f32x4;

__device__ inline unsigned short f2bf(float f) {
    unsigned int u = __builtin_bit_cast(unsigned int, f);
    unsigned int r = (u + 0x7FFFu + ((u >> 16) & 1u)) >> 16;   // RNE
    return (unsigned short)r;
}
__device__ inline unsigned int packbf(float a, float b) {
    return (unsigned int)f2bf(a) | ((unsigned int)f2bf(b) << 16);
}
__device__ inline float bf2f(unsigned int u16) {               // low 16 bits = bf16
    unsigned int t = u16 << 16;
    return __builtin_bit_cast(float, t);
}

// ---------------- embedding: xb[n] = bf16(embed[tok[n]]) packed 2/uint ----------------
__global__ void k_embed(const int* __restrict__ tok, const float* __restrict__ embed,
                        unsigned int* __restrict__ xb) {
    int gid = blockIdx.x * blockDim.x + threadIdx.x;   // n*32 + c
    if (gid >= N_NODES * 32) return;
    int n = gid >> 5, c = gid & 31;
    float2 v = ((const float2*)(embed + (long)tok[n] * HID))[c];
    xb[(long)n * 32 + c] = packbf(v.x, v.y);
}

// ---------------- degree / graph counts ----------------
__global__ void k_deg(const int* __restrict__ dst, int* __restrict__ cnt) {
    int e = blockIdx.x * blockDim.x + threadIdx.x;
    if (e < N_EDGES) atomicAdd(&cnt[dst[e]], 1);
}

__global__ void k_gcnt(const int* __restrict__ batch, int* __restrict__ gcnt) {
    int n = blockIdx.x * blockDim.x + threadIdx.x;
    if (n < N_NODES) atomicAdd(&gcnt[batch[n]], 1);
}

// ---------------- exclusive scan of cnt -> row_ptr ----------------
__global__ void k_scan1(const int* __restrict__ cnt, int* __restrict__ rel,
                        int* __restrict__ bsum) {
    __shared__ int sh[256];
    int i = blockIdx.x * 256 + threadIdx.x;
    int v = (i < N_NODES) ? cnt[i] : 0;
    sh[threadIdx.x] = v;
    __syncthreads();
    for (int o = 1; o < 256; o <<= 1) {
        int t = (threadIdx.x >= o) ? sh[threadIdx.x - o] : 0;
        __syncthreads();
        sh[threadIdx.x] += t;
        __syncthreads();
    }
    if (i < N_NODES) rel[i] = sh[threadIdx.x] - v;
    if (threadIdx.x == 255) bsum[blockIdx.x] = sh[255];
}

__global__ void k_scan2(int* __restrict__ bsum, int* __restrict__ boff) {
    __shared__ int sh[256];
    int i = threadIdx.x;
    int v = (i < SCAN_B) ? bsum[i] : 0;
    sh[i] = v;
    __syncthreads();
    for (int o = 1; o < 256; o <<= 1) {
        int t = (i >= o) ? sh[i - o] : 0;
        __syncthreads();
        sh[i] += t;
        __syncthreads();
    }
    if (i < SCAN_B) boff[i] = sh[i] - v;
}

__global__ void k_scan3(const int* __restrict__ rel, const int* __restrict__ boff,
                        int* __restrict__ row_ptr) {
    int i = blockIdx.x * 256 + threadIdx.x;
    if (i < N_NODES) row_ptr[i] = rel[i] + boff[blockIdx.x];
}

// ---------------- CSR fill ----------------
__global__ void k_fill(const int* __restrict__ src, const int* __restrict__ dst,
                       const int* __restrict__ row_ptr, int* __restrict__ cur,
                       int* __restrict__ esrc) {
    int e = blockIdx.x * blockDim.x + threadIdx.x;
    if (e >= N_EDGES) return;
    int d = dst[e];
    int pos = atomicAdd(&cur[d], 1);
    esrc[row_ptr[d] + pos] = src[e];
}

// ---------------- fused layer: gather-mean + [agg|x] @ [Wl|Wr]^T + bias + relu ----------------
// Block = 256 threads = 4 waves, 64 nodes. Wave w owns node strip [w*16, w*16+16):
//   aggregation accumulates in registers (2 bf16 channels/lane, 2 edges/wave-step),
//   writes wave-private LDS A rows, then MFMA (16x16x32 bf16) against cooperative B.
// Layer-1: store bf16 xout. Layer-2: relu + pool atomics into gsum (fp32).
#define AST 68   // uints per LDS row: 64 data + 4 pad
__global__ __launch_bounds__(256) void k_layer(
    const int* __restrict__ row_ptr, const int* __restrict__ cnt,
    const int* __restrict__ esrc, const unsigned int* __restrict__ xb,
    const float* __restrict__ Wl, const float* __restrict__ bl,
    const float* __restrict__ Wr,
    unsigned short* __restrict__ xoutb,
    const int* __restrict__ batch, float* __restrict__ gsum)
{
    __shared__ unsigned int As[64 * AST];   // [node][kpair]: 0..31 agg(mean), 32..63 x
    __shared__ unsigned int Bs[64 * AST];   // [h][kpair]:    0..31 Wl,        32..63 Wr
    const int tid = threadIdx.x;
    const int n0 = blockIdx.x * 64;

    // cooperative B stage: 64 rows x 64 uint (fp32 pair -> bf16 pair)
    for (int it = tid; it < 64 * 64; it += 256) {
        int h = it >> 6, c = it & 63;
        float2 v;
        if (c < 32) v = ((const float2*)(Wl + (long)h * HID))[c];
        else        v = ((const float2*)(Wr + (long)h * HID))[c - 32];
        Bs[h * AST + c] = packbf(v.x, v.y);
    }
    __syncthreads();

    const int lane = tid & 63;
    const int w    = tid >> 6;
    const int c    = lane & 31;   // channel pair: channels 2c, 2c+1
    const int p    = lane >> 5;   // edge-subset (even/odd)

    // aggregate my wave's 16 nodes
    for (int i = 0; i < 16; ++i) {
        int row  = w * 16 + i;
        int node = n0 + row;
        float ax = 0.f, ay = 0.f;
        int deg = 0;
        if (node < N_NODES) {
            int beg = row_ptr[node];
            deg = cnt[node];
            int end = beg + deg;
            for (int b = beg; b < end; b += 64) {
                int e = b + lane;
                int s = (e < end) ? esrc[e] : 0;
                int m = min(64, end - b);
                int j = 0;
                for (; j + 8 <= m; j += 8) {       // 4 steps x 2 edges, 4 loads in flight
                    int s0 = __shfl(s, j + 0 + p, 64);
                    int s1 = __shfl(s, j + 2 + p, 64);
                    int s2 = __shfl(s, j + 4 + p, 64);
                    int s3 = __shfl(s, j + 6 + p, 64);
                    unsigned int v0 = xb[(long)s0 * 32 + c];
                    unsigned int v1 = xb[(long)s1 * 32 + c];
                    unsigned int v2 = xb[(long)s2 * 32 + c];
                    unsigned int v3 = xb[(long)s3 * 32 + c];
                    ax += bf2f(v0 & 0xffff) + bf2f(v1 & 0xffff) +
                          bf2f(v2 & 0xffff) + bf2f(v3 & 0xffff);
                    ay += bf2f(v0 >> 16) + bf2f(v1 >> 16) +
                          bf2f(v2 >> 16) + bf2f(v3 >> 16);
                }
                for (; j < m; j += 2) {
                    if (j + p < m) {
                        int s0 = __shfl(s, j + p, 64);
                        unsigned int v = xb[(long)s0 * 32 + c];
                        ax += bf2f(v & 0xffff);
                        ay += bf2f(v >> 16);
                    }
                }
            }
        }
        // combine even/odd edge subsets
        ax += __shfl_xor(ax, 32, 64);
        ay += __shfl_xor(ay, 32, 64);
        if (p == 0) {
            float inv = 1.0f / (float)max(deg, 1);
            As[row * AST + c]      = packbf(ax * inv, ay * inv);
            As[row * AST + 32 + c] = (node < N_NODES) ? xb[(long)node * 32 + c] : 0u;
        }
    }
    // no barrier: wave reads only its own A rows; B already synced

    const int m    = lane & 15;
    const int quad = lane >> 4;
    const unsigned short* Ash = (const unsigned short*)As;
    const unsigned short* Bsh = (const unsigned short*)Bs;

    bf16x8 afr[4];
#pragma unroll
    for (int kst = 0; kst < 4; ++kst)
        afr[kst] = *(const bf16x8*)(Ash + (w * 16 + m) * (AST * 2) + kst * 32 + quad * 8);

    f32x4 acc[4];
#pragma unroll
    for (int t = 0; t < 4; ++t) {
        acc[t] = (f32x4){0.f, 0.f, 0.f, 0.f};
#pragma unroll
        for (int kst = 0; kst < 4; ++kst) {
            bf16x8 bfr = *(const bf16x8*)(Bsh + (t * 16 + m) * (AST * 2) + kst * 32 + quad * 8);
            acc[t] = __builtin_amdgcn_mfma_f32_16x16x32_bf16(afr[kst], bfr, acc[t], 0, 0, 0);
        }
    }

    // epilogue: C row = quad*4+r (node), col = m (h within tile t)
#pragma unroll
    for (int t = 0; t < 4; ++t) {
        int h = t * 16 + m;
        float bb = bl[h];
#pragma unroll
        for (int r = 0; r < 4; ++r) {
            int node = n0 + w * 16 + quad * 4 + r;
            if (node >= N_NODES) continue;
            float val = fmaxf(acc[t][r] + bb, 0.f);
            if (batch) {
                atomicAdd(&gsum[(long)batch[node] * HID + h], val);
            } else {
                xoutb[(long)node * HID + h] = f2bf(val);
            }
        }
    }
}

// ---------------- head ----------------
__global__ void k_final(const float* __restrict__ gsum, const int* __restrict__ gcnt,
                        const float* __restrict__ Wlin, const float* __restrict__ blin,
                        float* __restrict__ out) {
    int g = blockIdx.x, h = threadIdx.x;
    float v = gsum[(long)g * HID + h] / (float)max(gcnt[g], 1);
#pragma unroll
    for (int c = 0; c < NCLS; ++c) {
        float p = v * Wlin[c * HID + h];
        for (int o = 32; o > 0; o >>= 1) p += __shfl_down(p, o, 64);
        if (h == 0) out[g * NCLS + c] = p + blin[c];
    }
}

extern "C" void kernel_launch(void* const* d_in, const int* in_sizes, int n_in,
                              void* d_out, int out_size, void* d_ws, size_t ws_size,
                              hipStream_t stream) {
    const int*   tok   = (const int*)d_in[0];
    const int*   eidx  = (const int*)d_in[1];
    const int*   batch = (const int*)d_in[2];
    const float* embed = (const float*)d_in[3];
    const float* W1l   = (const float*)d_in[4];
    const float* b1l   = (const float*)d_in[5];
    const float* W1r   = (const float*)d_in[6];
    const float* W2l   = (const float*)d_in[7];
    const float* b2l   = (const float*)d_in[8];
    const float* W2r   = (const float*)d_in[9];
    const float* Wlin  = (const float*)d_in[10];
    const float* blin  = (const float*)d_in[11];
    float* out = (float*)d_out;

    const int* src = eidx;
    const int* dst = eidx + N_EDGES;

    char* wsp = (char*)d_ws;
    size_t off = 0;
    auto alloc = [&](size_t bytes) -> void* {
        void* p = wsp + off;
        off = (off + bytes + 255) & ~(size_t)255;
        return p;
    };
    unsigned int* x0b    = (unsigned int*)alloc((size_t)N_NODES * 32 * 4);  // bf16 packed
    unsigned int* x1b    = (unsigned int*)alloc((size_t)N_NODES * 32 * 4);
    int*   cnt     = (int*)  alloc((size_t)N_NODES * 4);
    int*   rel     = (int*)  alloc((size_t)N_NODES * 4);
    int*   row_ptr = (int*)  alloc((size_t)N_NODES * 4);
    int*   cur     = (int*)  alloc((size_t)N_NODES * 4);
    int*   bsum    = (int*)  alloc((size_t)SCAN_B * 4);
    int*   boff    = (int*)  alloc((size_t)SCAN_B * 4);
    int*   esrc    = (int*)  alloc((size_t)N_EDGES * 4);
    float* gsum    = (float*)alloc((size_t)N_GRAPHS * HID * 4);
    int*   gcnt    = (int*)  alloc((size_t)N_GRAPHS * 4);

    hipMemsetAsync(cnt,  0, (size_t)N_NODES * 4, stream);
    hipMemsetAsync(cur,  0, (size_t)N_NODES * 4, stream);
    hipMemsetAsync(gsum, 0, (size_t)N_GRAPHS * HID * 4, stream);
    hipMemsetAsync(gcnt, 0, (size_t)N_GRAPHS * 4, stream);

    k_embed<<<(N_NODES * 32 + 255) / 256, 256, 0, stream>>>(tok, embed, x0b);
    k_deg<<<(N_EDGES + 255) / 256, 256, 0, stream>>>(dst, cnt);
    k_gcnt<<<(N_NODES + 255) / 256, 256, 0, stream>>>(batch, gcnt);

    // CSR build
    k_scan1<<<SCAN_B, 256, 0, stream>>>(cnt, rel, bsum);
    k_scan2<<<1, 256, 0, stream>>>(bsum, boff);
    k_scan3<<<SCAN_B, 256, 0, stream>>>(rel, boff, row_ptr);
    k_fill<<<(N_EDGES + 255) / 256, 256, 0, stream>>>(src, dst, row_ptr, cur, esrc);

    const int LBLK = (N_NODES + 63) / 64;
    // Layer 1
    k_layer<<<LBLK, 256, 0, stream>>>(row_ptr, cnt, esrc, x0b, W1l, b1l, W1r,
                                      (unsigned short*)x1b, nullptr, nullptr);
    // Layer 2 (pool fused)
    k_layer<<<LBLK, 256, 0, stream>>>(row_ptr, cnt, esrc, x1b, W2l, b2l, W2r,
                                      nullptr, batch, gsum);

    k_final<<<N_GRAPHS, 64, 0, stream>>>(gsum, gcnt, Wlin, blin, out);
}

// Round 5
// 312.787 us; speedup vs baseline: 1.1309x; 1.1309x over previous
//
#include <hip/hip_runtime.h>

#define N_NODES  50000
#define N_EDGES  800000
#define N_GRAPHS 512
#define HID      64
#define NCLS     5
#define SCAN_B   ((N_NODES + 255) / 256)   // 196

typedef __attribute__((ext_vector_type(8))) short bf16x8;
typedef __attribute__((ext_vector_type(4))) float f32x4;

__device__ inline unsigned short f2bf(float f) {
    unsigned int u = __builtin_bit_cast(unsigned int, f);
    unsigned int r = (u + 0x7FFFu + ((u >> 16) & 1u)) >> 16;   // RNE
    return (unsigned short)r;
}
__device__ inline unsigned int packbf(float a, float b) {
    return (unsigned int)f2bf(a) | ((unsigned int)f2bf(b) << 16);
}
__device__ inline float bf2f(unsigned int u16) {
    unsigned int t = u16 << 16;
    return __builtin_bit_cast(float, t);
}

// ---------------- fused prep: embed-pack | deg | gcnt | pack W1 | pack W2 ----------------
#define EMB_T (N_NODES * 32)
#define PW_T  (64 * 64)
__global__ void k_prep(const int* __restrict__ tok, const float* __restrict__ embed,
                       unsigned int* __restrict__ x0b,
                       const int* __restrict__ dst, int* __restrict__ cnt,
                       const int* __restrict__ batch, int* __restrict__ gcnt,
                       const float* __restrict__ W1l, const float* __restrict__ W1r,
                       unsigned int* __restrict__ wb1,
                       const float* __restrict__ W2l, const float* __restrict__ W2r,
                       unsigned int* __restrict__ wb2) {
    int gid = blockIdx.x * blockDim.x + threadIdx.x;
    if (gid < EMB_T) {
        int n = gid >> 5, c = gid & 31;
        float2 v = ((const float2*)(embed + (long)tok[n] * HID))[c];
        x0b[(long)n * 32 + c] = packbf(v.x, v.y);
        return;
    }
    gid -= EMB_T;
    if (gid < N_EDGES) { atomicAdd(&cnt[dst[gid]], 1); return; }
    gid -= N_EDGES;
    if (gid < N_NODES) { atomicAdd(&gcnt[batch[gid]], 1); return; }
    gid -= N_NODES;
    if (gid < 2 * PW_T) {
        const float* Wl = (gid < PW_T) ? W1l : W2l;
        const float* Wr = (gid < PW_T) ? W1r : W2r;
        unsigned int* wb = (gid < PW_T) ? wb1 : wb2;
        int i = (gid < PW_T) ? gid : gid - PW_T;
        int h = i >> 6, c = i & 63;   // row h: uints 0..31 = Wl, 32..63 = Wr
        float2 v = (c < 32) ? ((const float2*)(Wl + (long)h * HID))[c]
                            : ((const float2*)(Wr + (long)h * HID))[c - 32];
        wb[i] = packbf(v.x, v.y);
    }
}
#define PREP_T (EMB_T + N_EDGES + N_NODES + 2 * PW_T)

// ---------------- exclusive scan of cnt -> row_ptr ----------------
__global__ void k_scan1(const int* __restrict__ cnt, int* __restrict__ rel,
                        int* __restrict__ bsum) {
    __shared__ int sh[256];
    int i = blockIdx.x * 256 + threadIdx.x;
    int v = (i < N_NODES) ? cnt[i] : 0;
    sh[threadIdx.x] = v;
    __syncthreads();
    for (int o = 1; o < 256; o <<= 1) {
        int t = (threadIdx.x >= o) ? sh[threadIdx.x - o] : 0;
        __syncthreads();
        sh[threadIdx.x] += t;
        __syncthreads();
    }
    if (i < N_NODES) rel[i] = sh[threadIdx.x] - v;
    if (threadIdx.x == 255) bsum[blockIdx.x] = sh[255];
}

__global__ void k_scan2(int* __restrict__ bsum, int* __restrict__ boff) {
    __shared__ int sh[256];
    int i = threadIdx.x;
    int v = (i < SCAN_B) ? bsum[i] : 0;
    sh[i] = v;
    __syncthreads();
    for (int o = 1; o < 256; o <<= 1) {
        int t = (i >= o) ? sh[i - o] : 0;
        __syncthreads();
        sh[i] += t;
        __syncthreads();
    }
    if (i < SCAN_B) boff[i] = sh[i] - v;
}

__global__ void k_scan3(const int* __restrict__ rel, const int* __restrict__ boff,
                        int* __restrict__ row_ptr) {
    int i = blockIdx.x * 256 + threadIdx.x;
    if (i < N_NODES) row_ptr[i] = rel[i] + boff[blockIdx.x];
}

// ---------------- CSR fill ----------------
__global__ void k_fill(const int* __restrict__ src, const int* __restrict__ dst,
                       const int* __restrict__ row_ptr, int* __restrict__ cur,
                       int* __restrict__ esrc) {
    int e = blockIdx.x * blockDim.x + threadIdx.x;
    if (e >= N_EDGES) return;
    int d = dst[e];
    int pos = atomicAdd(&cur[d], 1);
    esrc[row_ptr[d] + pos] = src[e];
}

// ---------------- gather-mean aggregation: one wave per dst node, bf16 packed ----------------
__global__ __launch_bounds__(256) void k_aggregate(
    const int* __restrict__ row_ptr, const int* __restrict__ cnt,
    const int* __restrict__ esrc, const unsigned int* __restrict__ xb,
    unsigned int* __restrict__ aggb) {
    int n = (blockIdx.x * blockDim.x + threadIdx.x) >> 6;
    int lane = threadIdx.x & 63;
    if (n >= N_NODES) return;
    int beg = row_ptr[n];
    int deg = cnt[n];
    int end = beg + deg;
    int c = lane & 31;   // channel pair: 2c, 2c+1
    int p = lane >> 5;   // edge parity
    float ax = 0.f, ay = 0.f;
    for (int b = beg; b < end; b += 64) {
        int e = b + lane;
        int s = (e < end) ? esrc[e] : 0;
        int mm = min(64, end - b);
        int j = 0;
        for (; j + 8 <= mm; j += 8) {        // 4 gathers in flight per lane
            int s0 = __shfl(s, j + 0 + p, 64);
            int s1 = __shfl(s, j + 2 + p, 64);
            int s2 = __shfl(s, j + 4 + p, 64);
            int s3 = __shfl(s, j + 6 + p, 64);
            unsigned int v0 = xb[(long)s0 * 32 + c];
            unsigned int v1 = xb[(long)s1 * 32 + c];
            unsigned int v2 = xb[(long)s2 * 32 + c];
            unsigned int v3 = xb[(long)s3 * 32 + c];
            ax += bf2f(v0 & 0xffff) + bf2f(v1 & 0xffff) +
                  bf2f(v2 & 0xffff) + bf2f(v3 & 0xffff);
            ay += bf2f(v0 >> 16) + bf2f(v1 >> 16) +
                  bf2f(v2 >> 16) + bf2f(v3 >> 16);
        }
        for (; j + p < mm; j += 2) {
            int s0 = __shfl(s, j + p, 64);
            unsigned int v = xb[(long)s0 * 32 + c];
            ax += bf2f(v & 0xffff);
            ay += bf2f(v >> 16);
        }
    }
    ax += __shfl_xor(ax, 32, 64);
    ay += __shfl_xor(ay, 32, 64);
    if (p == 0) {
        float inv = 1.0f / (float)max(deg, 1);
        aggb[(long)n * 32 + c] = packbf(ax * inv, ay * inv);
    }
}

// ---------------- transform: zero-LDS MFMA ----------------
// out[n][h] = relu( [agg | x] @ [Wl|Wr]^T + bl ), K=128 bf16.
// Wave w of block: nodes nb..nb+15 (nb = blk*64 + w*16). Fragments loaded
// directly from global in MFMA layout (A: agg/x rows; B: packed weight rows).
__global__ __launch_bounds__(256) void k_transform(
    const unsigned int* __restrict__ aggb, const unsigned int* __restrict__ xb,
    const unsigned int* __restrict__ wb, const float* __restrict__ bl,
    unsigned short* __restrict__ xoutb,
    const int* __restrict__ batch, float* __restrict__ gsum)
{
    const int tid  = threadIdx.x;
    const int lane = tid & 63;
    const int w    = tid >> 6;
    const int nb   = blockIdx.x * 64 + w * 16;
    const int m    = lane & 15;
    const int quad = lane >> 4;

    int row  = nb + m;
    int rowc = min(row, N_NODES - 1);

    // A fragments: kst*32 + quad*8 bf16 = uint offset kst*16 + quad*4
    bf16x8 afr[4];
    afr[0] = *(const bf16x8*)(aggb + (long)rowc * 32 + quad * 4);
    afr[1] = *(const bf16x8*)(aggb + (long)rowc * 32 + 16 + quad * 4);
    afr[2] = *(const bf16x8*)(xb + (long)rowc * 32 + quad * 4);
    afr[3] = *(const bf16x8*)(xb + (long)rowc * 32 + 16 + quad * 4);

    f32x4 acc[4];
#pragma unroll
    for (int t = 0; t < 4; ++t) {
        acc[t] = (f32x4){0.f, 0.f, 0.f, 0.f};
#pragma unroll
        for (int kst = 0; kst < 4; ++kst) {
            bf16x8 bfr = *(const bf16x8*)(wb + (t * 16 + m) * 64 + kst * 16 + quad * 4);
            acc[t] = __builtin_amdgcn_mfma_f32_16x16x32_bf16(afr[kst], bfr, acc[t], 0, 0, 0);
        }
    }

    // C layout: node = nb + quad*4 + r, h = t*16 + m
#pragma unroll
    for (int t = 0; t < 4; ++t) {
        int h = t * 16 + m;
        float bb = bl[h];
#pragma unroll
        for (int r = 0; r < 4; ++r) {
            int node = nb + quad * 4 + r;
            if (node >= N_NODES) continue;
            float val = fmaxf(acc[t][r] + bb, 0.f);
            if (batch) {
                atomicAdd(&gsum[(long)batch[node] * HID + h], val);
            } else {
                xoutb[(long)node * HID + h] = f2bf(val);
            }
        }
    }
}

// ---------------- head ----------------
__global__ void k_final(const float* __restrict__ gsum, const int* __restrict__ gcnt,
                        const float* __restrict__ Wlin, const float* __restrict__ blin,
                        float* __restrict__ out) {
    int g = blockIdx.x, h = threadIdx.x;
    float v = gsum[(long)g * HID + h] / (float)max(gcnt[g], 1);
#pragma unroll
    for (int c = 0; c < NCLS; ++c) {
        float p = v * Wlin[c * HID + h];
        for (int o = 32; o > 0; o >>= 1) p += __shfl_down(p, o, 64);
        if (h == 0) out[g * NCLS + c] = p + blin[c];
    }
}

extern "C" void kernel_launch(void* const* d_in, const int* in_sizes, int n_in,
                              void* d_out, int out_size, void* d_ws, size_t ws_size,
                              hipStream_t stream) {
    const int*   tok   = (const int*)d_in[0];
    const int*   eidx  = (const int*)d_in[1];
    const int*   batch = (const int*)d_in[2];
    const float* embed = (const float*)d_in[3];
    const float* W1l   = (const float*)d_in[4];
    const float* b1l   = (const float*)d_in[5];
    const float* W1r   = (const float*)d_in[6];
    const float* W2l   = (const float*)d_in[7];
    const float* b2l   = (const float*)d_in[8];
    const float* W2r   = (const float*)d_in[9];
    const float* Wlin  = (const float*)d_in[10];
    const float* blin  = (const float*)d_in[11];
    float* out = (float*)d_out;

    const int* src = eidx;
    const int* dst = eidx + N_EDGES;

    char* wsp = (char*)d_ws;
    size_t off = 0;
    auto alloc = [&](size_t bytes) -> void* {
        void* p = wsp + off;
        off = (off + bytes + 255) & ~(size_t)255;
        return p;
    };
    // cnt+cur adjacent (single memset); gsum+gcnt adjacent (single memset)
    int*   cnt     = (int*)  alloc((size_t)N_NODES * 4);     // 200192 aligned
    int*   cur     = (int*)  alloc((size_t)N_NODES * 4);
    float* gsum    = (float*)alloc((size_t)N_GRAPHS * HID * 4);
    int*   gcnt    = (int*)  alloc((size_t)N_GRAPHS * 4);
    int*   rel     = (int*)  alloc((size_t)N_NODES * 4);
    int*   row_ptr = (int*)  alloc((size_t)N_NODES * 4);
    int*   bsum    = (int*)  alloc((size_t)SCAN_B * 4);
    int*   boff    = (int*)  alloc((size_t)SCAN_B * 4);
    int*   esrc    = (int*)  alloc((size_t)N_EDGES * 4);
    unsigned int* x0b  = (unsigned int*)alloc((size_t)N_NODES * 32 * 4);
    unsigned int* x1b  = (unsigned int*)alloc((size_t)N_NODES * 32 * 4);
    unsigned int* aggb = (unsigned int*)alloc((size_t)N_NODES * 32 * 4);
    unsigned int* wb1  = (unsigned int*)alloc((size_t)64 * 64 * 4);
    unsigned int* wb2  = (unsigned int*)alloc((size_t)64 * 64 * 4);

    hipMemsetAsync(cnt, 0, (char*)cur - (char*)cnt + (size_t)N_NODES * 4, stream);
    hipMemsetAsync(gsum, 0, (char*)gcnt - (char*)gsum + (size_t)N_GRAPHS * 4, stream);

    k_prep<<<(PREP_T + 255) / 256, 256, 0, stream>>>(
        tok, embed, x0b, dst, cnt, batch, gcnt, W1l, W1r, wb1, W2l, W2r, wb2);

    // CSR build
    k_scan1<<<SCAN_B, 256, 0, stream>>>(cnt, rel, bsum);
    k_scan2<<<1, 256, 0, stream>>>(bsum, boff);
    k_scan3<<<SCAN_B, 256, 0, stream>>>(rel, boff, row_ptr);
    k_fill<<<(N_EDGES + 255) / 256, 256, 0, stream>>>(src, dst, row_ptr, cur, esrc);

    const int ABLK = (N_NODES * 64 + 255) / 256;
    const int TBLK = (N_NODES + 63) / 64;
    // Layer 1
    k_aggregate<<<ABLK, 256, 0, stream>>>(row_ptr, cnt, esrc, x0b, aggb);
    k_transform<<<TBLK, 256, 0, stream>>>(aggb, x0b, wb1, b1l,
                                          (unsigned short*)x1b, nullptr, nullptr);
    // Layer 2 (pool fused)
    k_aggregate<<<ABLK, 256, 0, stream>>>(row_ptr, cnt, esrc, x1b, aggb);
    k_transform<<<TBLK, 256, 0, stream>>>(aggb, x1b, wb2, b2l,
                                          nullptr, batch, gsum);

    k_final<<<N_GRAPHS, 64, 0, stream>>>(gsum, gcnt, Wlin, blin, out);
}

// Round 6
// 288.984 us; speedup vs baseline: 1.2240x; 1.0824x over previous
//
#include <hip/hip_runtime.h>

#define N_NODES  50000
#define N_EDGES  800000
#define N_GRAPHS 512
#define HID      64
#define NCLS     5
#define SCAN_B   ((N_NODES + 255) / 256)   // 196

typedef __attribute__((ext_vector_type(8))) short bf16x8;
typedef __attribute__((ext_vector_type(4))) float f32x4;

__device__ inline unsigned short f2bf(float f) {
    unsigned int u = __builtin_bit_cast(unsigned int, f);
    unsigned int r = (u + 0x7FFFu + ((u >> 16) & 1u)) >> 16;   // RNE
    return (unsigned short)r;
}
__device__ inline unsigned int packbf(float a, float b) {
    return (unsigned int)f2bf(a) | ((unsigned int)f2bf(b) << 16);
}
__device__ inline float bf2f(unsigned int u16) {
    unsigned int t = u16 << 16;
    return __builtin_bit_cast(float, t);
}

// ------- fused prep: embed-pack | deg atomics | batch boundaries | pack W1/W2 -------
#define EMB_T (N_NODES * 32)
#define PW_T  (64 * 64)
#define PREP_T (EMB_T + N_EDGES + N_NODES + 2 * PW_T)
__global__ void k_prep(const int* __restrict__ tok, const float* __restrict__ embed,
                       unsigned int* __restrict__ x0b,
                       const int* __restrict__ dst, int* __restrict__ cnt,
                       const int* __restrict__ batch,
                       int* __restrict__ pos_start, int* __restrict__ pos_end,
                       const float* __restrict__ W1l, const float* __restrict__ W1r,
                       unsigned int* __restrict__ wb1,
                       const float* __restrict__ W2l, const float* __restrict__ W2r,
                       unsigned int* __restrict__ wb2) {
    int gid = blockIdx.x * blockDim.x + threadIdx.x;
    if (gid < EMB_T) {
        int n = gid >> 5, c = gid & 31;
        float2 v = ((const float2*)(embed + (long)tok[n] * HID))[c];
        x0b[(long)n * 32 + c] = packbf(v.x, v.y);
        return;
    }
    gid -= EMB_T;
    if (gid < N_EDGES) { atomicAdd(&cnt[dst[gid]], 1); return; }
    gid -= N_EDGES;
    if (gid < N_NODES) {
        // batch is sorted: boundary threads write segment extents (no atomics)
        int n = gid;
        int b = batch[n];
        if (n == 0 || batch[n - 1] != b) pos_start[b] = n;
        if (n == N_NODES - 1 || batch[n + 1] != b) pos_end[b] = n + 1;
        return;
    }
    gid -= N_NODES;
    if (gid < 2 * PW_T) {
        const float* Wl = (gid < PW_T) ? W1l : W2l;
        const float* Wr = (gid < PW_T) ? W1r : W2r;
        unsigned int* wb = (gid < PW_T) ? wb1 : wb2;
        int i = (gid < PW_T) ? gid : gid - PW_T;
        int h = i >> 6, c = i & 63;   // row h: uints 0..31 = Wl, 32..63 = Wr
        float2 v = (c < 32) ? ((const float2*)(Wl + (long)h * HID))[c]
                            : ((const float2*)(Wr + (long)h * HID))[c - 32];
        wb[i] = packbf(v.x, v.y);
    }
}

// ---------------- exclusive scan of cnt -> row_ptr ----------------
__global__ void k_scan1(const int* __restrict__ cnt, int* __restrict__ rel,
                        int* __restrict__ bsum) {
    __shared__ int sh[256];
    int i = blockIdx.x * 256 + threadIdx.x;
    int v = (i < N_NODES) ? cnt[i] : 0;
    sh[threadIdx.x] = v;
    __syncthreads();
    for (int o = 1; o < 256; o <<= 1) {
        int t = (threadIdx.x >= o) ? sh[threadIdx.x - o] : 0;
        __syncthreads();
        sh[threadIdx.x] += t;
        __syncthreads();
    }
    if (i < N_NODES) rel[i] = sh[threadIdx.x] - v;
    if (threadIdx.x == 255) bsum[blockIdx.x] = sh[255];
}

__global__ void k_scan2(int* __restrict__ bsum, int* __restrict__ boff) {
    __shared__ int sh[256];
    int i = threadIdx.x;
    int v = (i < SCAN_B) ? bsum[i] : 0;
    sh[i] = v;
    __syncthreads();
    for (int o = 1; o < 256; o <<= 1) {
        int t = (i >= o) ? sh[i - o] : 0;
        __syncthreads();
        sh[i] += t;
        __syncthreads();
    }
    if (i < SCAN_B) boff[i] = sh[i] - v;
}

__global__ void k_scan3(const int* __restrict__ rel, const int* __restrict__ boff,
                        int* __restrict__ row_ptr) {
    int i = blockIdx.x * 256 + threadIdx.x;
    if (i < N_NODES) row_ptr[i] = rel[i] + boff[blockIdx.x];
}

// ---------------- CSR fill ----------------
__global__ void k_fill(const int* __restrict__ src, const int* __restrict__ dst,
                       const int* __restrict__ row_ptr, int* __restrict__ cur,
                       int* __restrict__ esrc) {
    int e = blockIdx.x * blockDim.x + threadIdx.x;
    if (e >= N_EDGES) return;
    int d = dst[e];
    int pos = atomicAdd(&cur[d], 1);
    esrc[row_ptr[d] + pos] = src[e];
}

// ------- gather-mean aggregation: one wave per dst node, 8 lanes x uint4 per edge -------
__global__ __launch_bounds__(256) void k_aggregate(
    const int* __restrict__ row_ptr, const int* __restrict__ cnt,
    const int* __restrict__ esrc, const unsigned int* __restrict__ xb,
    unsigned int* __restrict__ aggb) {
    int n    = (blockIdx.x * blockDim.x + threadIdx.x) >> 6;   // grid exact multiple
    int lane = threadIdx.x & 63;
    int q    = lane & 7;      // 16B chunk of the 128B feature row
    int e8   = lane >> 3;     // edge slot within group of 8
    int beg = row_ptr[n];
    int deg = cnt[n];
    int end = beg + deg;
    float f0 = 0, f1 = 0, f2 = 0, f3 = 0, f4 = 0, f5 = 0, f6 = 0, f7 = 0;
    for (int b = beg; b < end; b += 64) {
        int e = b + lane;
        int s = (e < end) ? esrc[e] : 0;
        int m = end - b;                       // edges in this tile (<=64 used)
#pragma unroll
        for (int g = 0; g < 8; ++g) {
            int j = g * 8 + e8;
            int sj = __shfl(s, j, 64);
            if (j < m) {
                uint4 v = *((const uint4*)(xb + (long)sj * 32) + q);
                f0 += bf2f(v.x & 0xffff); f1 += bf2f(v.x >> 16);
                f2 += bf2f(v.y & 0xffff); f3 += bf2f(v.y >> 16);
                f4 += bf2f(v.z & 0xffff); f5 += bf2f(v.z >> 16);
                f6 += bf2f(v.w & 0xffff); f7 += bf2f(v.w >> 16);
            }
        }
    }
    // reduce across the 8 edge slots (lane bits 3..5)
#pragma unroll
    for (int o = 8; o < 64; o <<= 1) {
        f0 += __shfl_xor(f0, o, 64); f1 += __shfl_xor(f1, o, 64);
        f2 += __shfl_xor(f2, o, 64); f3 += __shfl_xor(f3, o, 64);
        f4 += __shfl_xor(f4, o, 64); f5 += __shfl_xor(f5, o, 64);
        f6 += __shfl_xor(f6, o, 64); f7 += __shfl_xor(f7, o, 64);
    }
    if (e8 == 0) {
        float inv = 1.0f / (float)max(deg, 1);
        uint4 o;
        o.x = packbf(f0 * inv, f1 * inv);
        o.y = packbf(f2 * inv, f3 * inv);
        o.z = packbf(f4 * inv, f5 * inv);
        o.w = packbf(f6 * inv, f7 * inv);
        *((uint4*)(aggb + (long)n * 32) + q) = o;
    }
}

// ---------------- transform: zero-LDS MFMA ----------------
// out[n][h] = relu( [agg | x] @ [Wl|Wr]^T + bl ), K=128 bf16. Fragments direct
// from global (A: agg/x rows; B: fragment-ready packed weights, L2-hot).
__global__ __launch_bounds__(256) void k_transform(
    const unsigned int* __restrict__ aggb, const unsigned int* __restrict__ xb,
    const unsigned int* __restrict__ wb, const float* __restrict__ bl,
    unsigned short* __restrict__ xoutb,
    const int* __restrict__ batch, float* __restrict__ gsum)
{
    const int tid  = threadIdx.x;
    const int lane = tid & 63;
    const int w    = tid >> 6;
    const int nb   = blockIdx.x * 64 + w * 16;
    const int m    = lane & 15;
    const int quad = lane >> 4;

    int row  = nb + m;
    int rowc = min(row, N_NODES - 1);

    bf16x8 afr[4];
    afr[0] = *(const bf16x8*)(aggb + (long)rowc * 32 + quad * 4);
    afr[1] = *(const bf16x8*)(aggb + (long)rowc * 32 + 16 + quad * 4);
    afr[2] = *(const bf16x8*)(xb + (long)rowc * 32 + quad * 4);
    afr[3] = *(const bf16x8*)(xb + (long)rowc * 32 + 16 + quad * 4);

    f32x4 acc[4];
#pragma unroll
    for (int t = 0; t < 4; ++t) {
        acc[t] = (f32x4){0.f, 0.f, 0.f, 0.f};
#pragma unroll
        for (int kst = 0; kst < 4; ++kst) {
            bf16x8 bfr = *(const bf16x8*)(wb + (t * 16 + m) * 64 + kst * 16 + quad * 4);
            acc[t] = __builtin_amdgcn_mfma_f32_16x16x32_bf16(afr[kst], bfr, acc[t], 0, 0, 0);
        }
    }

#pragma unroll
    for (int t = 0; t < 4; ++t) {
        int h = t * 16 + m;
        float bb = bl[h];
#pragma unroll
        for (int r = 0; r < 4; ++r) {
            int node = nb + quad * 4 + r;
            if (node >= N_NODES) continue;
            float val = fmaxf(acc[t][r] + bb, 0.f);
            if (batch) {
                atomicAdd(&gsum[(long)batch[node] * HID + h], val);
            } else {
                xoutb[(long)node * HID + h] = f2bf(val);
            }
        }
    }
}

// ---------------- head ----------------
__global__ void k_final(const float* __restrict__ gsum,
                        const int* __restrict__ pos_start, const int* __restrict__ pos_end,
                        const float* __restrict__ Wlin, const float* __restrict__ blin,
                        float* __restrict__ out) {
    int g = blockIdx.x, h = threadIdx.x;
    int cntg = pos_end[g] - pos_start[g];
    float v = gsum[(long)g * HID + h] / (float)max(cntg, 1);
#pragma unroll
    for (int c = 0; c < NCLS; ++c) {
        float p = v * Wlin[c * HID + h];
        for (int o = 32; o > 0; o >>= 1) p += __shfl_down(p, o, 64);
        if (h == 0) out[g * NCLS + c] = p + blin[c];
    }
}

extern "C" void kernel_launch(void* const* d_in, const int* in_sizes, int n_in,
                              void* d_out, int out_size, void* d_ws, size_t ws_size,
                              hipStream_t stream) {
    const int*   tok   = (const int*)d_in[0];
    const int*   eidx  = (const int*)d_in[1];
    const int*   batch = (const int*)d_in[2];
    const float* embed = (const float*)d_in[3];
    const float* W1l   = (const float*)d_in[4];
    const float* b1l   = (const float*)d_in[5];
    const float* W1r   = (const float*)d_in[6];
    const float* W2l   = (const float*)d_in[7];
    const float* b2l   = (const float*)d_in[8];
    const float* W2r   = (const float*)d_in[9];
    const float* Wlin  = (const float*)d_in[10];
    const float* blin  = (const float*)d_in[11];
    float* out = (float*)d_out;

    const int* src = eidx;
    const int* dst = eidx + N_EDGES;

    char* wsp = (char*)d_ws;
    size_t off = 0;
    auto alloc = [&](size_t bytes) -> void* {
        void* p = wsp + off;
        off = (off + bytes + 255) & ~(size_t)255;
        return p;
    };
    // cnt+cur adjacent (memset 1); gsum+pos_start+pos_end adjacent (memset 2)
    int*   cnt     = (int*)  alloc((size_t)N_NODES * 4);
    int*   cur     = (int*)  alloc((size_t)N_NODES * 4);
    float* gsum    = (float*)alloc((size_t)N_GRAPHS * HID * 4);
    int*   pstart  = (int*)  alloc((size_t)N_GRAPHS * 4);
    int*   pend    = (int*)  alloc((size_t)N_GRAPHS * 4);
    int*   rel     = (int*)  alloc((size_t)N_NODES * 4);
    int*   row_ptr = (int*)  alloc((size_t)N_NODES * 4);
    int*   bsum    = (int*)  alloc((size_t)SCAN_B * 4);
    int*   boff    = (int*)  alloc((size_t)SCAN_B * 4);
    int*   esrc    = (int*)  alloc((size_t)N_EDGES * 4);
    unsigned int* x0b  = (unsigned int*)alloc((size_t)N_NODES * 32 * 4);
    unsigned int* x1b  = (unsigned int*)alloc((size_t)N_NODES * 32 * 4);
    unsigned int* aggb = (unsigned int*)alloc((size_t)N_NODES * 32 * 4);
    unsigned int* wb1  = (unsigned int*)alloc((size_t)64 * 64 * 4);
    unsigned int* wb2  = (unsigned int*)alloc((size_t)64 * 64 * 4);

    hipMemsetAsync(cnt, 0, (char*)cur - (char*)cnt + (size_t)N_NODES * 4, stream);
    hipMemsetAsync(gsum, 0, (char*)pend - (char*)gsum + (size_t)N_GRAPHS * 4, stream);

    k_prep<<<(PREP_T + 255) / 256, 256, 0, stream>>>(
        tok, embed, x0b, dst, cnt, batch, pstart, pend, W1l, W1r, wb1, W2l, W2r, wb2);

    // CSR build
    k_scan1<<<SCAN_B, 256, 0, stream>>>(cnt, rel, bsum);
    k_scan2<<<1, 256, 0, stream>>>(bsum, boff);
    k_scan3<<<SCAN_B, 256, 0, stream>>>(rel, boff, row_ptr);
    k_fill<<<(N_EDGES + 255) / 256, 256, 0, stream>>>(src, dst, row_ptr, cur, esrc);

    const int ABLK = (N_NODES * 64) / 256;   // exact
    const int TBLK = (N_NODES + 63) / 64;
    // Layer 1
    k_aggregate<<<ABLK, 256, 0, stream>>>(row_ptr, cnt, esrc, x0b, aggb);
    k_transform<<<TBLK, 256, 0, stream>>>(aggb, x0b, wb1, b1l,
                                          (unsigned short*)x1b, nullptr, nullptr);
    // Layer 2 (pool fused)
    k_aggregate<<<ABLK, 256, 0, stream>>>(row_ptr, cnt, esrc, x1b, aggb);
    k_transform<<<TBLK, 256, 0, stream>>>(aggb, x1b, wb2, b2l,
                                          nullptr, batch, gsum);

    k_final<<<N_GRAPHS, 64, 0, stream>>>(gsum, pstart, pend, Wlin, blin, out);
}